// Round 1
// baseline (646.589 us; speedup 1.0000x reference)
//
#include <hip/hip_runtime.h>

// PolyFeatures: out[b] = concat([1], z[b], {z_i*z_j : i<=j}) for D=96.
// Write-BW-bound: 623 MB out vs 12.6 MB in.

constexpr int D       = 96;
constexpr int NQ      = D * (D + 1) / 2;   // 4656
constexpr int ROW_OUT = 1 + D + NQ;        // 4753
constexpr int RPB     = 8;                 // rows per block
constexpr int BLK     = 256;
constexpr int NIT     = (ROW_OUT + BLK - 1) / BLK;  // 19

__device__ __forceinline__ int triu_off(int i) {
    // start index of row i in the upper-triangle enumeration (i<=j, row-major)
    return i * (2 * D + 1 - i) / 2;
}

__global__ __launch_bounds__(BLK) void PolyFeatures_kernel(
        const float* __restrict__ z, float* __restrict__ out, int nrows) {
    __shared__ float sh[RPB][D + 1];   // [r][96] = 1.0f slot
    const int tid = threadIdx.x;
    const long long row0 = (long long)blockIdx.x * RPB;

    // ---- Per-block: decode output index k -> (a,b) LDS byte offsets, kept in
    // registers. Same for every row, so amortized across RPB rows.
    unsigned desc[NIT];
#pragma unroll
    for (int it = 0; it < NIT; ++it) {
        int k = it * BLK + tid;
        int a, c;
        if (k >= ROW_OUT) {
            a = D; c = D;                 // dummy (masked by guard below)
        } else if (k == 0) {
            a = D; c = D;                 // 1.0 * 1.0
        } else if (k <= D) {
            a = k - 1; c = D;             // z[k-1] * 1.0
        } else {
            int t = k - (D + 1);          // 0 .. NQ-1
            float disc = (2.0f * D + 1.0f) * (2.0f * D + 1.0f) - 8.0f * (float)t;
            int i = (int)((2.0f * D + 1.0f - sqrtf(disc)) * 0.5f);
            if (i > 0 && triu_off(i) > t) --i;
            while (triu_off(i + 1) <= t) ++i;
            int j = i + (t - triu_off(i));
            a = i; c = j;
        }
        desc[it] = ((unsigned)(a * 4) << 16) | (unsigned)(c * 4);
    }

    // ---- Stage RPB rows into LDS (contiguous, coalesced).
    const float* src = z + row0 * D;
    for (int idx = tid; idx < RPB * D; idx += BLK) {
        long long grow = row0 + idx / D;
        if (grow < nrows) {
            int r = idx / D, col = idx - (idx / D) * D;
            sh[r][col] = src[idx];
        }
    }
    if (tid < RPB) sh[tid][D] = 1.0f;
    __syncthreads();

    // ---- Emit: every element is sh[a] * sh[c]; stores lane-consecutive.
#pragma unroll
    for (int r = 0; r < RPB; ++r) {
        if (row0 + r >= nrows) break;
        const char* shb = (const char*)&sh[r][0];
        float* dst = out + (row0 + r) * (long long)ROW_OUT;
#pragma unroll
        for (int it = 0; it < NIT; ++it) {
            int k = it * BLK + tid;
            if (k < ROW_OUT) {
                unsigned d2 = desc[it];
                float va = *(const float*)(shb + (d2 >> 16));
                float vc = *(const float*)(shb + (d2 & 0xffffu));
                dst[k] = va * vc;
            }
        }
    }
}

extern "C" void kernel_launch(void* const* d_in, const int* in_sizes, int n_in,
                              void* d_out, int out_size, void* d_ws, size_t ws_size,
                              hipStream_t stream) {
    const float* z = (const float*)d_in[0];
    float* out = (float*)d_out;
    const int nrows = in_sizes[0] / D;              // 32768
    const int grid = (nrows + RPB - 1) / RPB;       // 4096
    PolyFeatures_kernel<<<grid, BLK, 0, stream>>>(z, out, nrows);
}